// Round 4
// baseline (396.952 us; speedup 1.0000x reference)
//
#include <hip/hip_runtime.h>
#include <hip/hip_bf16.h>
#include <hip/hip_fp16.h>

#define D 128
#define NXCD 8
#define SLOTL 3
#define SLOT (1 << SLOTL)          // 8 slots per (node, xcd); per-cell deg ~Poisson(2)
#define NODE_STRIDE (NXCD * SLOT)  // 64 ints per node in ep (same 25.6MB as proven layout)
#define OVF 8                      // shared overflow slots per node (device-scope fallback)

typedef _Float16 half8 __attribute__((ext_vector_type(8)));
typedef _Float16 half4 __attribute__((ext_vector_type(4)));
typedef float f32x4 __attribute__((ext_vector_type(4)));

// XCC (XCD) id of the CU this wave runs on. hwreg(id=20, offset=0, size=4).
__device__ __forceinline__ int xcc_id() {
    return __builtin_amdgcn_s_getreg((3 << 11) | (0 << 6) | 20) & (NXCD - 1);
}

// ============ W prep: WT[n][k] = (fp16) W[k][n], both weights ============

__global__ void k_prepW2(const float* __restrict__ W1, const float* __restrict__ W2,
                         _Float16* __restrict__ WT1, _Float16* __restrict__ WT2) {
    const int i = blockIdx.x * 256 + threadIdx.x;
    if (i < 2 * D * D) {
        const float* W = (i < D * D) ? W1 : W2;
        _Float16* WT   = (i < D * D) ? WT1 : WT2;
        const int j = (i < D * D) ? i : i - D * D;
        const int k = j >> 7, n = j & 127;
        WT[n * D + k] = (_Float16)W[j];
    }
}

// ============ GEMM body (A from global) ============

template <typename AT>
__device__ __forceinline__ void gemm_body(int bid, const AT* __restrict__ A,
                                          const _Float16* __restrict__ WT,
                                          _Float16* __restrict__ Hout, int nrows) {
    const int wv   = threadIdx.x >> 6;
    const int lane = threadIdx.x & 63;
    const int l    = lane & 15;
    const int quad = lane >> 4;
    const int base = bid * 64 + wv * 16;
    int row = base + l;
    const bool valid = row < nrows;
    if (!valid) row = nrows - 1;

    half8 af[4];
    const AT* Ar = &A[(size_t)row * D + quad * 8];
    #pragma unroll
    for (int s = 0; s < 4; ++s) {
        if constexpr (sizeof(AT) == 4) {
            const float4 v0 = *(const float4*)(Ar + s * 32);
            const float4 v1 = *(const float4*)(Ar + s * 32 + 4);
            af[s][0] = (_Float16)v0.x; af[s][1] = (_Float16)v0.y;
            af[s][2] = (_Float16)v0.z; af[s][3] = (_Float16)v0.w;
            af[s][4] = (_Float16)v1.x; af[s][5] = (_Float16)v1.y;
            af[s][6] = (_Float16)v1.z; af[s][7] = (_Float16)v1.w;
        } else {
            af[s] = *(const half8*)(Ar + s * 32);
        }
    }

    f32x4 acc[8];
    #pragma unroll
    for (int t = 0; t < 8; ++t) acc[t] = (f32x4)0.0f;

    #pragma unroll
    for (int s = 0; s < 4; ++s) {
        #pragma unroll
        for (int t = 0; t < 8; ++t) {
            const half8 wf = *(const half8*)&WT[(size_t)(t * 16 + l) * D + s * 32 + quad * 8];
            acc[t] = __builtin_amdgcn_mfma_f32_16x16x32_f16(wf, af[s], acc[t], 0, 0, 0);
        }
    }

    if (valid) {
        _Float16* Or = &Hout[(size_t)row * D + quad * 4];
        #pragma unroll
        for (int t = 0; t < 8; ++t) {
            half4 o;
            o[0] = (_Float16)acc[t][0]; o[1] = (_Float16)acc[t][1];
            o[2] = (_Float16)acc[t][2]; o[3] = (_Float16)acc[t][3];
            *(half4*)(Or + t * 16) = o;
        }
    }
}

// ============ fused: GEMM1 ∥ hist + padded-CSR scatter ============
// PRIV=1: workgroup-scope atomics on XCD-private counters execute in the
// LOCAL XCD L2 (all CUs of an XCD share it), bypassing the ~14 G/s
// device-coherence-point wall measured in rounds 0-2. 8 private slots per
// (node,xcd); rare cell overflow (P~2.3e-4/cell) takes the exact
// device-scope path into epo. PRIV=0: proven round-2 device-scope scheme
// (ws_size fallback), single 64-slot segment, same ep layout.

template <bool PRIV>
__launch_bounds__(256)
__global__ void k_fused1(const int* __restrict__ src, const int* __restrict__ dst,
                         int* __restrict__ cnt, int* __restrict__ ovfc,
                         int* __restrict__ ep, int* __restrict__ epo,
                         int E, int gblocks,
                         const float* __restrict__ A, const _Float16* __restrict__ WT,
                         _Float16* __restrict__ Hout, int nrows) {
    if ((int)blockIdx.x < gblocks) {
        gemm_body<float>((int)blockIdx.x, A, WT, Hout, nrows);
        return;
    }
    size_t cbase = 0;
    int xoff = 0;
    if constexpr (PRIV) {
        const int x = xcc_id();
        cbase = (size_t)x * (size_t)nrows;
        xoff  = x << SLOTL;
    }

    auto edge_one = [&](int d, int s) {
        if constexpr (PRIV) {
            const int r = __hip_atomic_fetch_add(&cnt[cbase + d], 1,
                                                 __ATOMIC_RELAXED, __HIP_MEMORY_SCOPE_WORKGROUP);
            if (r < SLOT) {
                ep[((size_t)d << 6) + xoff + r] = s;
            } else {
                const int r2 = atomicAdd(&ovfc[d], 1);
                if (r2 < OVF) epo[(size_t)d * OVF + r2] = s;
            }
        } else {
            const int r = atomicAdd(&cnt[d], 1);
            if (r < NODE_STRIDE) ep[((size_t)d << 6) + r] = s;
        }
    };

    const int i4 = (((int)blockIdx.x - gblocks) * 256 + threadIdx.x) * 4;
    if (i4 + 4 <= E) {
        const int4 d4 = *(const int4*)(dst + i4);
        const int4 s4 = *(const int4*)(src + i4);
        edge_one(d4.x, s4.x);
        edge_one(d4.y, s4.y);
        edge_one(d4.z, s4.z);
        edge_one(d4.w, s4.w);
    } else {
        for (int i = i4; i < E; ++i) edge_one(dst[i], src[i]);
    }
}

// ============ fold counts -> per-node meta + packed segment counts ============
// meta[i] = true_degree (8b) | stored_overflow<<8 ; segAB = 8x clamped counts.
// PRIV=0: one segment holding min(cnt,64), no overflow -> agg_row degenerates
// to the old contiguous walk.

template <bool PRIV>
__global__ void k_sum(const int* __restrict__ cnt, const int* __restrict__ ovfc,
                      uint2* __restrict__ segAB, unsigned* __restrict__ meta, int n) {
    const int i = blockIdx.x * 256 + threadIdx.x;
    if (i >= n) return;
    if constexpr (PRIV) {
        int tot = 0;
        unsigned lo = 0, hi = 0;
        #pragma unroll
        for (int x = 0; x < 4; ++x) {
            const int c = cnt[(size_t)x * n + i];
            tot += c;
            lo |= (unsigned)min(c, SLOT) << (8 * x);
        }
        #pragma unroll
        for (int x = 4; x < 8; ++x) {
            const int c = cnt[(size_t)x * n + i];
            tot += c;
            hi |= (unsigned)min(c, SLOT) << (8 * (x - 4));
        }
        const int ov = min(ovfc[i], OVF);
        segAB[i] = make_uint2(lo, hi);
        meta[i]  = (unsigned)min(tot, 255) | ((unsigned)ov << 8);
    } else {
        const int c = cnt[i];
        segAB[i] = make_uint2((unsigned)min(c, NODE_STRIDE), 0u);
        meta[i]  = (unsigned)min(c, 255);
    }
}

// ============ agg row body: 8 packed segments + overflow, 8-deep MLP ============
// dis folded as rsqrtf(1 + deg) from meta (proven ~17us win vs dis array).
// Segment select is fully unrolled, compile-time-indexed (no scratch).

__device__ __forceinline__ float4 agg_row(const _Float16* __restrict__ h,
                                          const unsigned* __restrict__ meta,
                                          const uint2* __restrict__ segAB,
                                          const int* __restrict__ ep,
                                          const int* __restrict__ epo,
                                          int row, int lane) {
    const int c4 = lane * 4;
    const unsigned mr = meta[row];
    const int cr = mr & 0xff;
    const float dd = rsqrtf(1.0f + (float)cr);
    const float sw = dd * dd;
    const half4 hv = *(const half4*)&h[(size_t)row * D + c4];
    float4 acc = make_float4((float)hv[0] * sw, (float)hv[1] * sw,
                             (float)hv[2] * sw, (float)hv[3] * sw);

    const uint2 seg = segAB[row];
    int pre[9];
    pre[0] = 0;
    #pragma unroll
    for (int t = 0; t < 4; ++t) pre[t + 1] = pre[t] + (int)((seg.x >> (8 * t)) & 0xff);
    #pragma unroll
    for (int t = 4; t < 8; ++t) pre[t + 1] = pre[t] + (int)((seg.y >> (8 * (t - 4))) & 0xff);
    const int ovn  = (int)((mr >> 8) & 0xff);
    const int degR = pre[8] + ovn;
    const int baseMain = row << 6;  // row * NODE_STRIDE

    for (int c = 0; c < degR; c += 32) {
        const int j = c + lane;
        int sv = 0;
        if (j < degR) {
            if (j < pre[8]) {
                int x = 0, prex = 0;
                #pragma unroll
                for (int t = 1; t < 8; ++t)
                    if (j >= pre[t]) { x = t; prex = pre[t]; }
                sv = ep[baseMain + (x << SLOTL) + (j - prex)];
            } else {
                sv = epo[(size_t)row * OVF + (j - pre[8])];
            }
        }
        const float wl = rsqrtf(1.0f + (float)(meta[sv] & 0xff)) * dd;
        const int m = min(32, degR - c);
        int k = 0;
        for (; k + 8 <= m; k += 8) {
            int   s[8];
            float w[8];
            half4 v[8];
            #pragma unroll
            for (int u = 0; u < 8; ++u) {
                s[u] = __shfl(sv, k + u, 32);
                w[u] = __shfl(wl, k + u, 32);
            }
            #pragma unroll
            for (int u = 0; u < 8; ++u)
                v[u] = *(const half4*)&h[(size_t)s[u] * D + c4];
            #pragma unroll
            for (int u = 0; u < 8; ++u) {
                acc.x = fmaf((float)v[u][0], w[u], acc.x);
                acc.y = fmaf((float)v[u][1], w[u], acc.y);
                acc.z = fmaf((float)v[u][2], w[u], acc.z);
                acc.w = fmaf((float)v[u][3], w[u], acc.w);
            }
        }
        for (; k + 4 <= m; k += 4) {
            int   s[4];
            float w[4];
            half4 v[4];
            #pragma unroll
            for (int u = 0; u < 4; ++u) {
                s[u] = __shfl(sv, k + u, 32);
                w[u] = __shfl(wl, k + u, 32);
            }
            #pragma unroll
            for (int u = 0; u < 4; ++u)
                v[u] = *(const half4*)&h[(size_t)s[u] * D + c4];
            #pragma unroll
            for (int u = 0; u < 4; ++u) {
                acc.x = fmaf((float)v[u][0], w[u], acc.x);
                acc.y = fmaf((float)v[u][1], w[u], acc.y);
                acc.z = fmaf((float)v[u][2], w[u], acc.z);
                acc.w = fmaf((float)v[u][3], w[u], acc.w);
            }
        }
        for (; k < m; ++k) {
            const int   s = __shfl(sv, k, 32);
            const float w = __shfl(wl, k, 32);
            const half4 v = *(const half4*)&h[(size_t)s * D + c4];
            acc.x = fmaf((float)v[0], w, acc.x);
            acc.y = fmaf((float)v[1], w, acc.y);
            acc.z = fmaf((float)v[2], w, acc.z);
            acc.w = fmaf((float)v[3], w, acc.w);
        }
    }
    return acc;
}

// ============ fused agg(layer1) + GEMM2: 32 rows / 128 threads ============

#define LSTRIDE 136  // _Float16 units (272 B row stride, 16B-aligned)

__launch_bounds__(128)
__global__ void k_agg_gemm2(const _Float16* __restrict__ h,
                            const unsigned* __restrict__ meta, const uint2* __restrict__ segAB,
                            const int* __restrict__ ep, const int* __restrict__ epo,
                            const float* __restrict__ bias, const _Float16* __restrict__ WT,
                            _Float16* __restrict__ Hout, int n) {
    __shared__ _Float16 sh[32 * LSTRIDE];

    const int r0   = blockIdx.x * 32;
    const int hw   = threadIdx.x >> 5;   // 0..3
    const int lane = threadIdx.x & 31;
    const int c4   = lane * 4;

    #pragma unroll 1
    for (int i = 0; i < 8; ++i) {
        const int rl  = hw * 8 + i;
        const int row = r0 + rl;
        half4 o;
        if (row < n) {
            float4 acc = agg_row(h, meta, segAB, ep, epo, row, lane);
            const float4 bb = *(const float4*)&bias[c4];
            o[0] = (_Float16)fmaxf(acc.x + bb.x, 0.f);
            o[1] = (_Float16)fmaxf(acc.y + bb.y, 0.f);
            o[2] = (_Float16)fmaxf(acc.z + bb.z, 0.f);
            o[3] = (_Float16)fmaxf(acc.w + bb.w, 0.f);
        } else {
            o[0] = o[1] = o[2] = o[3] = (_Float16)0.f;
        }
        *(half4*)&sh[rl * LSTRIDE + c4] = o;
    }
    __syncthreads();

    const int wv   = threadIdx.x >> 6;   // 0..1
    const int wl64 = threadIdx.x & 63;
    const int l    = wl64 & 15;
    const int quad = wl64 >> 4;
    const int rl   = wv * 16 + l;
    const int row  = r0 + rl;

    half8 af[4];
    #pragma unroll
    for (int s = 0; s < 4; ++s)
        af[s] = *(const half8*)&sh[rl * LSTRIDE + s * 32 + quad * 8];

    f32x4 acc[8];
    #pragma unroll
    for (int t = 0; t < 8; ++t) acc[t] = (f32x4)0.0f;

    #pragma unroll
    for (int s = 0; s < 4; ++s) {
        #pragma unroll
        for (int t = 0; t < 8; ++t) {
            const half8 wf = *(const half8*)&WT[(size_t)(t * 16 + l) * D + s * 32 + quad * 8];
            acc[t] = __builtin_amdgcn_mfma_f32_16x16x32_f16(wf, af[s], acc[t], 0, 0, 0);
        }
    }

    if (row < n) {
        _Float16* Or = &Hout[(size_t)row * D + quad * 4];
        #pragma unroll
        for (int t = 0; t < 8; ++t) {
            half4 o;
            o[0] = (_Float16)acc[t][0]; o[1] = (_Float16)acc[t][1];
            o[2] = (_Float16)acc[t][2]; o[3] = (_Float16)acc[t][3];
            *(half4*)(Or + t * 16) = o;
        }
    }
}

// ============ final agg (layer2) -> fp32 d_out ============

__launch_bounds__(256)
__global__ void k_agg_out(const _Float16* __restrict__ h,
                          const unsigned* __restrict__ meta, const uint2* __restrict__ segAB,
                          const int* __restrict__ ep, const int* __restrict__ epo,
                          const float* __restrict__ bias, float* __restrict__ out, int n) {
    const int row = blockIdx.x * 8 + (threadIdx.x >> 5);
    if (row >= n) return;
    const int lane = threadIdx.x & 31;
    const int c4 = lane * 4;

    float4 acc = agg_row(h, meta, segAB, ep, epo, row, lane);
    const float4 bb = *(const float4*)&bias[c4];
    acc.x = fmaxf(acc.x + bb.x, 0.f);
    acc.y = fmaxf(acc.y + bb.y, 0.f);
    acc.z = fmaxf(acc.z + bb.z, 0.f);
    acc.w = fmaxf(acc.w + bb.w, 0.f);
    *(float4*)&out[(size_t)row * D + c4] = acc;
}

// ================= launch =================

extern "C" void kernel_launch(void* const* d_in, const int* in_sizes, int n_in,
                              void* d_out, int out_size, void* d_ws, size_t ws_size,
                              hipStream_t stream) {
    const float* x  = (const float*)d_in[0];
    const int*   ei = (const int*)d_in[1];
    const float* W1 = (const float*)d_in[2];
    const float* b1 = (const float*)d_in[3];
    const float* W2 = (const float*)d_in[4];
    const float* b2 = (const float*)d_in[5];

    const int N = in_sizes[0] / D;     // 100000
    const int E = in_sizes[1] / 2;     // 1600000
    const int* src = ei;
    const int* dst = ei + E;
    float* out = (float*)d_out;

    auto A256 = [](size_t v) { return (v + 255) & ~(size_t)255; };

    // --- private (XCD-local atomic) layout, ~85 MB ---
    size_t need_priv = A256((size_t)NXCD * N * 4) + A256((size_t)N * 4) + A256((size_t)N * 4)
                     + A256((size_t)N * 8) + 2 * A256((size_t)D * D * 2)
                     + A256((size_t)N * NODE_STRIDE * 4) + A256((size_t)N * OVF * 4)
                     + 2 * A256((size_t)N * D * 2);
    const bool priv = (ws_size == 0) || (need_priv <= ws_size);

    char* w = (char*)d_ws;
    int *cnt, *ovfc, *ep, *epo;
    unsigned* meta;
    uint2* segAB;
    _Float16 *WT1, *WT2, *hA, *hB;

    if (priv) {
        cnt   = (int*)w;      w += A256((size_t)NXCD * N * 4);
        ovfc  = (int*)w;      w += A256((size_t)N * 4);
    } else {
        cnt   = (int*)w;      w += A256((size_t)N * 4);
        ovfc  = cnt;  // unused in fallback
    }
    meta  = (unsigned*)w; w += A256((size_t)N * 4);
    segAB = (uint2*)w;    w += A256((size_t)N * 8);
    WT1   = (_Float16*)w; w += A256((size_t)D * D * 2);
    WT2   = (_Float16*)w; w += A256((size_t)D * D * 2);
    ep    = (int*)w;      w += A256((size_t)N * NODE_STRIDE * 4);
    if (priv) {
        epo = (int*)w;    w += A256((size_t)N * OVF * 4);
    } else {
        epo = ep;  // never dereferenced in fallback (ovn == 0 everywhere)
    }
    hA = (_Float16*)w;    w += A256((size_t)N * D * 2);
    hB = (_Float16*)w;

    const int egrid = (E / 4 + 255) / 256;   // 1563 edge blocks (4 edges/thread)
    const int ggrid = (N + 63) / 64;         // 1563 GEMM blocks

    if (priv) {
        hipMemsetAsync(cnt, 0, (size_t)NXCD * N * 4, stream);
        hipMemsetAsync(ovfc, 0, (size_t)N * 4, stream);
    } else {
        hipMemsetAsync(cnt, 0, (size_t)N * 4, stream);
    }
    k_prepW2<<<(2 * D * D + 255) / 256, 256, 0, stream>>>(W1, W2, WT1, WT2);

    // GEMM1 blocks first, edge scatter trickles in behind them (overlap, proven r1/r2)
    if (priv)
        k_fused1<true><<<ggrid + egrid, 256, 0, stream>>>(src, dst, cnt, ovfc, ep, epo,
                                                          E, ggrid, x, WT1, hA, N);
    else
        k_fused1<false><<<ggrid + egrid, 256, 0, stream>>>(src, dst, cnt, ovfc, ep, epo,
                                                           E, ggrid, x, WT1, hA, N);

    // fold counts -> meta/segments (coalesced, ~3us)
    if (priv)
        k_sum<true><<<(N + 255) / 256, 256, 0, stream>>>(cnt, ovfc, segAB, meta, N);
    else
        k_sum<false><<<(N + 255) / 256, 256, 0, stream>>>(cnt, ovfc, segAB, meta, N);

    // agg(layer1) + GEMM2 fused, 32 rows/block
    k_agg_gemm2<<<(N + 31) / 32, 128, 0, stream>>>(hA, meta, segAB, ep, epo, b1, WT2, hB, N);

    // final aggregation -> d_out
    k_agg_out<<<(N + 7) / 8, 256, 0, stream>>>(hB, meta, segAB, ep, epo, b2, out, N);
}

// Round 5
// 382.778 us; speedup vs baseline: 1.0370x; 1.0370x over previous
//
#include <hip/hip_runtime.h>
#include <hip/hip_bf16.h>
#include <hip/hip_fp16.h>

#define D 128
#define CAP 64   // padded CSR slot capacity; P(deg>=64)~1e-16 for Poisson(16)

typedef _Float16 half8 __attribute__((ext_vector_type(8)));
typedef _Float16 half4 __attribute__((ext_vector_type(4)));
typedef float f32x4 __attribute__((ext_vector_type(4)));

// ============ W prep: WT[n][k] = (fp16) W[k][n], both weights ============

__global__ void k_prepW2(const float* __restrict__ W1, const float* __restrict__ W2,
                         _Float16* __restrict__ WT1, _Float16* __restrict__ WT2) {
    const int i = blockIdx.x * 256 + threadIdx.x;
    if (i < 2 * D * D) {
        const float* W = (i < D * D) ? W1 : W2;
        _Float16* WT   = (i < D * D) ? WT1 : WT2;
        const int j = (i < D * D) ? i : i - D * D;
        const int k = j >> 7, n = j & 127;
        WT[n * D + k] = (_Float16)W[j];
    }
}

// ============ GEMM body (A from global) ============

template <typename AT>
__device__ __forceinline__ void gemm_body(int bid, const AT* __restrict__ A,
                                          const _Float16* __restrict__ WT,
                                          _Float16* __restrict__ Hout, int nrows) {
    const int wv   = threadIdx.x >> 6;
    const int lane = threadIdx.x & 63;
    const int l    = lane & 15;
    const int quad = lane >> 4;
    const int base = bid * 64 + wv * 16;
    int row = base + l;
    const bool valid = row < nrows;
    if (!valid) row = nrows - 1;

    half8 af[4];
    const AT* Ar = &A[(size_t)row * D + quad * 8];
    #pragma unroll
    for (int s = 0; s < 4; ++s) {
        if constexpr (sizeof(AT) == 4) {
            const float4 v0 = *(const float4*)(Ar + s * 32);
            const float4 v1 = *(const float4*)(Ar + s * 32 + 4);
            af[s][0] = (_Float16)v0.x; af[s][1] = (_Float16)v0.y;
            af[s][2] = (_Float16)v0.z; af[s][3] = (_Float16)v0.w;
            af[s][4] = (_Float16)v1.x; af[s][5] = (_Float16)v1.y;
            af[s][6] = (_Float16)v1.z; af[s][7] = (_Float16)v1.w;
        } else {
            af[s] = *(const half8*)(Ar + s * 32);
        }
    }

    f32x4 acc[8];
    #pragma unroll
    for (int t = 0; t < 8; ++t) acc[t] = (f32x4)0.0f;

    #pragma unroll
    for (int s = 0; s < 4; ++s) {
        #pragma unroll
        for (int t = 0; t < 8; ++t) {
            const half8 wf = *(const half8*)&WT[(size_t)(t * 16 + l) * D + s * 32 + quad * 8];
            acc[t] = __builtin_amdgcn_mfma_f32_16x16x32_f16(wf, af[s], acc[t], 0, 0, 0);
        }
    }

    if (valid) {
        _Float16* Or = &Hout[(size_t)row * D + quad * 4];
        #pragma unroll
        for (int t = 0; t < 8; ++t) {
            half4 o;
            o[0] = (_Float16)acc[t][0]; o[1] = (_Float16)acc[t][1];
            o[2] = (_Float16)acc[t][2]; o[3] = (_Float16)acc[t][3];
            *(half4*)(Or + t * 16) = o;
        }
    }
}

// ============ fused: GEMM1 ∥ hist + padded-CSR scatter ============
// Round-0 edge path restored verbatim: 1 edge/thread, device-scope atomic,
// contiguous CAP=64 slots. Proven 109±1 us (r0); 4/thread showed 110-137
// variance (r2); XCD-private scope was null-to-negative (r4). GEMM blocks
// first so the latency-bound scatter trickles in behind them (r1 lesson).

__launch_bounds__(256)
__global__ void k_fused1(const int* __restrict__ src, const int* __restrict__ dst,
                         int* __restrict__ cnt, int* __restrict__ ep, int E, int gblocks,
                         const float* __restrict__ A, const _Float16* __restrict__ WT,
                         _Float16* __restrict__ Hout, int nrows) {
    if ((int)blockIdx.x < gblocks) {
        gemm_body<float>((int)blockIdx.x, A, WT, Hout, nrows);
        return;
    }
    const int i = ((int)blockIdx.x - gblocks) * 256 + threadIdx.x;
    if (i < E) {
        const int d = dst[i];
        const int r = atomicAdd(&cnt[d], 1);
        if (r < CAP) ep[(size_t)d * CAP + r] = src[i];
    }
}

// ============ agg: row-level software pipeline + 16-deep gather groups ============
// dis folded as rsqrtf(1+cnt) (proven ~17us win). Prefetch pulls the serial
// head of row i+1 (cnt -> hv -> ep chunk -> cnt[sv] gather) ahead of row i's
// FMA phase, doubling per-warp memory concurrency on the L3-gather path.

struct RowPref {
    int   cr;   // cnt[row]
    int   sv;   // this lane's first-chunk source index (0 if lane >= deg)
    float ds;   // rsqrtf(1 + cnt[sv])
    half4 hv;   // self row, this lane's 4 columns
};

__device__ __forceinline__ void agg_prefetch(const _Float16* __restrict__ h,
                                             const int* __restrict__ cnt,
                                             const int* __restrict__ ep,
                                             int row, int lane, RowPref& p) {
    p.cr = cnt[row];
    p.hv = *(const half4*)&h[(size_t)row * D + lane * 4];
    const int deg = min(p.cr, CAP);
    int sv = 0;
    if (lane < deg) sv = ep[(size_t)row * CAP + lane];
    p.sv = sv;
    p.ds = rsqrtf(1.0f + (float)cnt[sv]);
}

template <int U>
__device__ __forceinline__ void grp(const _Float16* __restrict__ h, int c4,
                                    int sv, float wl, int k, float4& acc) {
    int s[U]; float w[U]; half4 v[U];
    #pragma unroll
    for (int u = 0; u < U; ++u) {
        s[u] = __shfl(sv, k + u, 32);
        w[u] = __shfl(wl, k + u, 32);
    }
    #pragma unroll
    for (int u = 0; u < U; ++u)
        v[u] = *(const half4*)&h[(size_t)s[u] * D + c4];
    #pragma unroll
    for (int u = 0; u < U; ++u) {
        acc.x = fmaf((float)v[u][0], w[u], acc.x);
        acc.y = fmaf((float)v[u][1], w[u], acc.y);
        acc.z = fmaf((float)v[u][2], w[u], acc.z);
        acc.w = fmaf((float)v[u][3], w[u], acc.w);
    }
}

__device__ __forceinline__ float4 agg_compute(const _Float16* __restrict__ h,
                                              const int* __restrict__ cnt,
                                              const int* __restrict__ ep,
                                              int row, int lane, const RowPref& p) {
    const int c4 = lane * 4;
    const float dd = rsqrtf(1.0f + (float)p.cr);
    const float sw = dd * dd;
    float4 acc = make_float4((float)p.hv[0] * sw, (float)p.hv[1] * sw,
                             (float)p.hv[2] * sw, (float)p.hv[3] * sw);
    const int deg = min(p.cr, CAP);
    int sv = p.sv;
    float wl = p.ds * dd;

    for (int c = 0; c < deg; c += 32) {
        if (c > 0) {  // later chunks (deg>32, ~1.5e-4 of rows): load inline
            sv = 0;
            if (c + lane < deg) sv = ep[(size_t)row * CAP + c + lane];
            wl = rsqrtf(1.0f + (float)cnt[sv]) * dd;
        }
        const int m = min(32, deg - c);
        int k = 0;
        for (; k + 16 <= m; k += 16) grp<16>(h, c4, sv, wl, k, acc);
        for (; k + 8 <= m; k += 8)   grp<8>(h, c4, sv, wl, k, acc);
        for (; k + 4 <= m; k += 4)   grp<4>(h, c4, sv, wl, k, acc);
        for (; k < m; ++k)           grp<1>(h, c4, sv, wl, k, acc);
    }
    return acc;
}

// ============ fused agg(layer1) + GEMM2: 32 rows / 128 threads ============

#define LSTRIDE 136  // _Float16 units (272 B row stride, 16B-aligned)

__launch_bounds__(128)
__global__ void k_agg_gemm2(const _Float16* __restrict__ h,
                            const int* __restrict__ cnt, const int* __restrict__ ep,
                            const float* __restrict__ bias, const _Float16* __restrict__ WT,
                            _Float16* __restrict__ Hout, int n) {
    __shared__ _Float16 sh[32 * LSTRIDE];

    const int r0   = blockIdx.x * 32;
    const int hw   = threadIdx.x >> 5;   // 0..3
    const int lane = threadIdx.x & 31;
    const int c4   = lane * 4;
    const float4 bb = *(const float4*)&bias[c4];

    RowPref p;
    agg_prefetch(h, cnt, ep, min(r0 + hw * 8, n - 1), lane, p);

    #pragma unroll 1
    for (int i = 0; i < 8; ++i) {
        const int rl   = hw * 8 + i;
        const int row  = r0 + rl;
        const int rowc = min(row, n - 1);
        RowPref pn = p;
        if (i < 7) agg_prefetch(h, cnt, ep, min(row + 1, n - 1), lane, pn);
        half4 o;
        if (row < n) {
            float4 acc = agg_compute(h, cnt, ep, rowc, lane, p);
            o[0] = (_Float16)fmaxf(acc.x + bb.x, 0.f);
            o[1] = (_Float16)fmaxf(acc.y + bb.y, 0.f);
            o[2] = (_Float16)fmaxf(acc.z + bb.z, 0.f);
            o[3] = (_Float16)fmaxf(acc.w + bb.w, 0.f);
        } else {
            o[0] = o[1] = o[2] = o[3] = (_Float16)0.f;
        }
        *(half4*)&sh[rl * LSTRIDE + c4] = o;
        p = pn;
    }
    __syncthreads();

    const int wv   = threadIdx.x >> 6;   // 0..1
    const int wl64 = threadIdx.x & 63;
    const int l    = wl64 & 15;
    const int quad = wl64 >> 4;
    const int rl   = wv * 16 + l;
    const int row  = r0 + rl;

    half8 af[4];
    #pragma unroll
    for (int s = 0; s < 4; ++s)
        af[s] = *(const half8*)&sh[rl * LSTRIDE + s * 32 + quad * 8];

    f32x4 acc[8];
    #pragma unroll
    for (int t = 0; t < 8; ++t) acc[t] = (f32x4)0.0f;

    #pragma unroll
    for (int s = 0; s < 4; ++s) {
        #pragma unroll
        for (int t = 0; t < 8; ++t) {
            const half8 wf = *(const half8*)&WT[(size_t)(t * 16 + l) * D + s * 32 + quad * 8];
            acc[t] = __builtin_amdgcn_mfma_f32_16x16x32_f16(wf, af[s], acc[t], 0, 0, 0);
        }
    }

    if (row < n) {
        _Float16* Or = &Hout[(size_t)row * D + quad * 4];
        #pragma unroll
        for (int t = 0; t < 8; ++t) {
            half4 o;
            o[0] = (_Float16)acc[t][0]; o[1] = (_Float16)acc[t][1];
            o[2] = (_Float16)acc[t][2]; o[3] = (_Float16)acc[t][3];
            *(half4*)(Or + t * 16) = o;
        }
    }
}

// ============ final agg (layer2) -> fp32 d_out: 2 rows per 32-lane group ============

__launch_bounds__(256)
__global__ void k_agg_out(const _Float16* __restrict__ h,
                          const int* __restrict__ cnt, const int* __restrict__ ep,
                          const float* __restrict__ bias, float* __restrict__ out, int n) {
    const int r0 = blockIdx.x * 16 + ((threadIdx.x >> 5) << 1);
    if (r0 >= n) return;
    const int lane = threadIdx.x & 31;
    const int c4 = lane * 4;
    const float4 bb = *(const float4*)&bias[c4];
    const int r1 = min(r0 + 1, n - 1);

    RowPref p0, p1;
    agg_prefetch(h, cnt, ep, r0, lane, p0);
    agg_prefetch(h, cnt, ep, r1, lane, p1);

    float4 a0 = agg_compute(h, cnt, ep, r0, lane, p0);
    a0.x = fmaxf(a0.x + bb.x, 0.f);
    a0.y = fmaxf(a0.y + bb.y, 0.f);
    a0.z = fmaxf(a0.z + bb.z, 0.f);
    a0.w = fmaxf(a0.w + bb.w, 0.f);
    *(float4*)&out[(size_t)r0 * D + c4] = a0;

    if (r0 + 1 < n) {
        float4 a1 = agg_compute(h, cnt, ep, r1, lane, p1);
        a1.x = fmaxf(a1.x + bb.x, 0.f);
        a1.y = fmaxf(a1.y + bb.y, 0.f);
        a1.z = fmaxf(a1.z + bb.z, 0.f);
        a1.w = fmaxf(a1.w + bb.w, 0.f);
        *(float4*)&out[(size_t)(r0 + 1) * D + c4] = a1;
    }
}

// ================= launch =================

extern "C" void kernel_launch(void* const* d_in, const int* in_sizes, int n_in,
                              void* d_out, int out_size, void* d_ws, size_t ws_size,
                              hipStream_t stream) {
    const float* x  = (const float*)d_in[0];
    const int*   ei = (const int*)d_in[1];
    const float* W1 = (const float*)d_in[2];
    const float* b1 = (const float*)d_in[3];
    const float* W2 = (const float*)d_in[4];
    const float* b2 = (const float*)d_in[5];

    const int N = in_sizes[0] / D;     // 100000
    const int E = in_sizes[1] / 2;     // 1600000
    const int* src = ei;
    const int* dst = ei + E;
    float* out = (float*)d_out;

    auto align256 = [](size_t v) { return (v + 255) & ~(size_t)255; };
    char* w = (char*)d_ws;
    int*      cnt = (int*)w;      w += align256((size_t)N * 4);
    _Float16* WT1 = (_Float16*)w; w += align256((size_t)D * D * 2);
    _Float16* WT2 = (_Float16*)w; w += align256((size_t)D * D * 2);
    int*      ep  = (int*)w;      w += align256((size_t)N * CAP * 4);
    _Float16* hA  = (_Float16*)w; w += align256((size_t)N * D * 2);
    _Float16* hB  = (_Float16*)w;

    const int egrid = (E + 255) / 256;     // 6250 edge blocks (1 edge/thread, r0-proven)
    const int ggrid = (N + 63) / 64;       // 1563 GEMM blocks

    hipMemsetAsync(cnt, 0, (size_t)N * 4, stream);
    k_prepW2<<<(2 * D * D + 255) / 256, 256, 0, stream>>>(W1, W2, WT1, WT2);

    // GEMM1 blocks first, edge scatter trickles in behind them (overlap)
    k_fused1<<<ggrid + egrid, 256, 0, stream>>>(src, dst, cnt, ep, E, ggrid, x, WT1, hA, N);

    // agg(layer1) + GEMM2 fused, 32 rows/block, row-pipelined
    k_agg_gemm2<<<(N + 31) / 32, 128, 0, stream>>>(hA, cnt, ep, b1, WT2, hB, N);

    // final aggregation -> d_out, 2 rows per 32-lane group, pair-pipelined
    k_agg_out<<<(N + 15) / 16, 256, 0, stream>>>(hB, cnt, ep, b2, out, N);
}

// Round 6
// 369.915 us; speedup vs baseline: 1.0731x; 1.0348x over previous
//
#include <hip/hip_runtime.h>
#include <hip/hip_bf16.h>
#include <hip/hip_fp16.h>

#define D 128
#define CAP 64   // padded CSR slot capacity; P(deg>=64)~1e-16 for Poisson(16)

typedef _Float16 half8 __attribute__((ext_vector_type(8)));
typedef _Float16 half4 __attribute__((ext_vector_type(4)));
typedef float f32x4 __attribute__((ext_vector_type(4)));

// ============ W prep: WT[n][k] = (fp16) W[k][n], both weights ============

__global__ void k_prepW2(const float* __restrict__ W1, const float* __restrict__ W2,
                         _Float16* __restrict__ WT1, _Float16* __restrict__ WT2) {
    const int i = blockIdx.x * 256 + threadIdx.x;
    if (i < 2 * D * D) {
        const float* W = (i < D * D) ? W1 : W2;
        _Float16* WT   = (i < D * D) ? WT1 : WT2;
        const int j = (i < D * D) ? i : i - D * D;
        const int k = j >> 7, n = j & 127;
        WT[n * D + k] = (_Float16)W[j];
    }
}

// ============ GEMM body (A from global), templated output type ============

template <typename AT, typename OT>
__device__ __forceinline__ void gemm_body(int bid, const AT* __restrict__ A,
                                          const _Float16* __restrict__ WT,
                                          OT* __restrict__ Hout, int nrows) {
    const int wv   = threadIdx.x >> 6;
    const int lane = threadIdx.x & 63;
    const int l    = lane & 15;
    const int quad = lane >> 4;
    const int base = bid * 64 + wv * 16;
    int row = base + l;
    const bool valid = row < nrows;
    if (!valid) row = nrows - 1;

    half8 af[4];
    const AT* Ar = &A[(size_t)row * D + quad * 8];
    #pragma unroll
    for (int s = 0; s < 4; ++s) {
        if constexpr (sizeof(AT) == 4) {
            const float4 v0 = *(const float4*)(Ar + s * 32);
            const float4 v1 = *(const float4*)(Ar + s * 32 + 4);
            af[s][0] = (_Float16)v0.x; af[s][1] = (_Float16)v0.y;
            af[s][2] = (_Float16)v0.z; af[s][3] = (_Float16)v0.w;
            af[s][4] = (_Float16)v1.x; af[s][5] = (_Float16)v1.y;
            af[s][6] = (_Float16)v1.z; af[s][7] = (_Float16)v1.w;
        } else {
            af[s] = *(const half8*)(Ar + s * 32);
        }
    }

    f32x4 acc[8];
    #pragma unroll
    for (int t = 0; t < 8; ++t) acc[t] = (f32x4)0.0f;

    #pragma unroll
    for (int s = 0; s < 4; ++s) {
        #pragma unroll
        for (int t = 0; t < 8; ++t) {
            const half8 wf = *(const half8*)&WT[(size_t)(t * 16 + l) * D + s * 32 + quad * 8];
            acc[t] = __builtin_amdgcn_mfma_f32_16x16x32_f16(wf, af[s], acc[t], 0, 0, 0);
        }
    }

    if (valid) {
        OT* Or = &Hout[(size_t)row * D + quad * 4];
        #pragma unroll
        for (int t = 0; t < 8; ++t) {
            if constexpr (sizeof(OT) == 2) {
                half4 o;
                o[0] = (_Float16)acc[t][0]; o[1] = (_Float16)acc[t][1];
                o[2] = (_Float16)acc[t][2]; o[3] = (_Float16)acc[t][3];
                *(half4*)(Or + t * 16) = o;
            } else {
                float4 o = make_float4(acc[t][0], acc[t][1], acc[t][2], acc[t][3]);
                *(float4*)(Or + t * 16) = o;
            }
        }
    }
}

// ============ fused: GEMM1 ∥ hist + padded-CSR scatter ============
// Edge path = round-0 form verbatim: 1 edge/thread, device-scope atomic
// (proven 109±1 us; 4/thread = 110-137 variance r2; XCD-private scope
// null-to-negative r4). GEMM blocks first so the scatter trickles in
// behind them (r1: edge-first serialized phases, +74 us).

template <bool F32OUT>
__launch_bounds__(256)
__global__ void k_fused1(const int* __restrict__ src, const int* __restrict__ dst,
                         int* __restrict__ cnt, int* __restrict__ ep, int E, int gblocks,
                         const float* __restrict__ A, const _Float16* __restrict__ WT,
                         void* __restrict__ Hout, int nrows) {
    if ((int)blockIdx.x < gblocks) {
        if constexpr (F32OUT)
            gemm_body<float, float>((int)blockIdx.x, A, WT, (float*)Hout, nrows);
        else
            gemm_body<float, _Float16>((int)blockIdx.x, A, WT, (_Float16*)Hout, nrows);
        return;
    }
    const int i = ((int)blockIdx.x - gblocks) * 256 + threadIdx.x;
    if (i < E) {
        const int d = dst[i];
        const int r = atomicAdd(&cnt[d], 1);
        if (r < CAP) ep[(size_t)d * CAP + r] = src[i];
    }
}

// ============ k_scale: g[v] = fp16(dis[v] * y[v]) — N-scale, not E-scale ============
// Moves the norm factor dis[src] out of the per-edge path entirely:
// sum_s dis_s*dis_d*y_s = dis_d * sum_s g_s. The per-edge cnt[sv] gather,
// rsqrt, and weight-shfl all disappear from the agg critical chain.
// F32IN=1: single fp16 rounding (same count as baseline). 8 elems/thread.

template <bool F32IN>
__global__ void k_scale(const void* __restrict__ hA, const int* __restrict__ cnt,
                        _Float16* __restrict__ g, int n) {
    const int t = blockIdx.x * 256 + threadIdx.x;   // one thread = 8 columns
    if (t >= n * (D / 8)) return;
    const int row = t >> 4;
    const int c8  = (t & 15) * 8;
    const float dd = rsqrtf(1.0f + (float)cnt[row]);
    half8 o;
    if constexpr (F32IN) {
        const float* a = (const float*)hA + (size_t)row * D + c8;
        const float4 v0 = *(const float4*)a;
        const float4 v1 = *(const float4*)(a + 4);
        o[0] = (_Float16)(v0.x * dd); o[1] = (_Float16)(v0.y * dd);
        o[2] = (_Float16)(v0.z * dd); o[3] = (_Float16)(v0.w * dd);
        o[4] = (_Float16)(v1.x * dd); o[5] = (_Float16)(v1.y * dd);
        o[6] = (_Float16)(v1.z * dd); o[7] = (_Float16)(v1.w * dd);
    } else {
        const half8 v = *(const half8*)((const _Float16*)hA + (size_t)row * D + c8);
        #pragma unroll
        for (int u = 0; u < 8; ++u) o[u] = (_Float16)((float)v[u] * dd);
    }
    *(half8*)&g[(size_t)row * D + c8] = o;
}

// ============ agg over pre-scaled g: pure gather+add, r2-simple structure ============
// Per chunk chain is now ep -> shfl -> gathers (one memory round-trip
// removed vs the weighted form). Self term = g[row] (carries dis[row]);
// caller multiplies the sum by dis[row].

__device__ __forceinline__ float4 agg_g(const _Float16* __restrict__ g,
                                        const int* __restrict__ ep,
                                        int row, int deg, int lane) {
    const int c4 = lane * 4;
    const half4 s0 = *(const half4*)&g[(size_t)row * D + c4];
    float4 acc = make_float4((float)s0[0], (float)s0[1], (float)s0[2], (float)s0[3]);
    const size_t base = (size_t)row * CAP;

    for (int c = 0; c < deg; c += 32) {
        int sv = 0;
        if (c + lane < deg) sv = ep[base + c + lane];
        const int m = min(32, deg - c);
        int k = 0;
        for (; k + 8 <= m; k += 8) {
            int s[8]; half4 v[8];
            #pragma unroll
            for (int u = 0; u < 8; ++u) s[u] = __shfl(sv, k + u, 32);
            #pragma unroll
            for (int u = 0; u < 8; ++u)
                v[u] = *(const half4*)&g[(size_t)s[u] * D + c4];
            #pragma unroll
            for (int u = 0; u < 8; ++u) {
                acc.x += (float)v[u][0];
                acc.y += (float)v[u][1];
                acc.z += (float)v[u][2];
                acc.w += (float)v[u][3];
            }
        }
        for (; k + 4 <= m; k += 4) {
            int s[4]; half4 v[4];
            #pragma unroll
            for (int u = 0; u < 4; ++u) s[u] = __shfl(sv, k + u, 32);
            #pragma unroll
            for (int u = 0; u < 4; ++u)
                v[u] = *(const half4*)&g[(size_t)s[u] * D + c4];
            #pragma unroll
            for (int u = 0; u < 4; ++u) {
                acc.x += (float)v[u][0];
                acc.y += (float)v[u][1];
                acc.z += (float)v[u][2];
                acc.w += (float)v[u][3];
            }
        }
        for (; k < m; ++k) {
            const int s = __shfl(sv, k, 32);
            const half4 v = *(const half4*)&g[(size_t)s * D + c4];
            acc.x += (float)v[0];
            acc.y += (float)v[1];
            acc.z += (float)v[2];
            acc.w += (float)v[3];
        }
    }
    return acc;
}

// ============ fused agg(layer1) + GEMM2: 32 rows / 128 threads ============
// Epilogue writes g2 = fp16(dis[row] * (h1·W2)) — layer-2's pre-scaling is
// free here (single rounding, dis from L2-hot cnt).

#define LSTRIDE 136  // _Float16 units (272 B row stride, 16B-aligned)

__launch_bounds__(128)
__global__ void k_agg_gemm2(const _Float16* __restrict__ g, const int* __restrict__ cnt,
                            const int* __restrict__ ep, const float* __restrict__ bias,
                            const _Float16* __restrict__ WT,
                            _Float16* __restrict__ Gout, int n) {
    __shared__ _Float16 sh[32 * LSTRIDE];

    const int r0   = blockIdx.x * 32;
    const int hw   = threadIdx.x >> 5;   // 0..3
    const int lane = threadIdx.x & 31;
    const int c4   = lane * 4;
    const float4 bb = *(const float4*)&bias[c4];

    #pragma unroll 1
    for (int i = 0; i < 8; ++i) {
        const int rl  = hw * 8 + i;
        const int row = r0 + rl;
        half4 o;
        if (row < n) {
            const int cr = cnt[row];
            const float dd = rsqrtf(1.0f + (float)cr);
            float4 acc = agg_g(g, ep, row, min(cr, CAP), lane);
            o[0] = (_Float16)fmaxf(fmaf(acc.x, dd, bb.x), 0.f);
            o[1] = (_Float16)fmaxf(fmaf(acc.y, dd, bb.y), 0.f);
            o[2] = (_Float16)fmaxf(fmaf(acc.z, dd, bb.z), 0.f);
            o[3] = (_Float16)fmaxf(fmaf(acc.w, dd, bb.w), 0.f);
        } else {
            o[0] = o[1] = o[2] = o[3] = (_Float16)0.f;
        }
        *(half4*)&sh[rl * LSTRIDE + c4] = o;
    }
    __syncthreads();

    const int wv   = threadIdx.x >> 6;   // 0..1
    const int wl64 = threadIdx.x & 63;
    const int l    = wl64 & 15;
    const int quad = wl64 >> 4;
    const int rl   = wv * 16 + l;
    const int row  = r0 + rl;

    half8 af[4];
    #pragma unroll
    for (int s = 0; s < 4; ++s)
        af[s] = *(const half8*)&sh[rl * LSTRIDE + s * 32 + quad * 8];

    f32x4 acc[8];
    #pragma unroll
    for (int t = 0; t < 8; ++t) acc[t] = (f32x4)0.0f;

    #pragma unroll
    for (int s = 0; s < 4; ++s) {
        #pragma unroll
        for (int t = 0; t < 8; ++t) {
            const half8 wf = *(const half8*)&WT[(size_t)(t * 16 + l) * D + s * 32 + quad * 8];
            acc[t] = __builtin_amdgcn_mfma_f32_16x16x32_f16(wf, af[s], acc[t], 0, 0, 0);
        }
    }

    if (row < n) {
        const float ddr = rsqrtf(1.0f + (float)cnt[row]);
        _Float16* Or = &Gout[(size_t)row * D + quad * 4];
        #pragma unroll
        for (int t = 0; t < 8; ++t) {
            half4 o;
            o[0] = (_Float16)(acc[t][0] * ddr); o[1] = (_Float16)(acc[t][1] * ddr);
            o[2] = (_Float16)(acc[t][2] * ddr); o[3] = (_Float16)(acc[t][3] * ddr);
            *(half4*)(Or + t * 16) = o;
        }
    }
}

// ============ final agg (layer2) -> fp32 d_out: r0-simple, 8 rows / 256 thr ============

__launch_bounds__(256)
__global__ void k_agg_out(const _Float16* __restrict__ g2, const int* __restrict__ cnt,
                          const int* __restrict__ ep, const float* __restrict__ bias,
                          float* __restrict__ out, int n) {
    const int row = blockIdx.x * 8 + (threadIdx.x >> 5);
    if (row >= n) return;
    const int lane = threadIdx.x & 31;
    const int c4 = lane * 4;
    const float4 bb = *(const float4*)&bias[c4];

    const int cr = cnt[row];
    const float dd = rsqrtf(1.0f + (float)cr);
    float4 acc = agg_g(g2, ep, row, min(cr, CAP), lane);
    acc.x = fmaxf(fmaf(acc.x, dd, bb.x), 0.f);
    acc.y = fmaxf(fmaf(acc.y, dd, bb.y), 0.f);
    acc.z = fmaxf(fmaf(acc.z, dd, bb.z), 0.f);
    acc.w = fmaxf(fmaf(acc.w, dd, bb.w), 0.f);
    *(float4*)&out[(size_t)row * D + c4] = acc;
}

// ================= launch =================

extern "C" void kernel_launch(void* const* d_in, const int* in_sizes, int n_in,
                              void* d_out, int out_size, void* d_ws, size_t ws_size,
                              hipStream_t stream) {
    const float* x  = (const float*)d_in[0];
    const int*   ei = (const int*)d_in[1];
    const float* W1 = (const float*)d_in[2];
    const float* b1 = (const float*)d_in[3];
    const float* W2 = (const float*)d_in[4];
    const float* b2 = (const float*)d_in[5];

    const int N = in_sizes[0] / D;     // 100000
    const int E = in_sizes[1] / 2;     // 1600000
    const int* src = ei;
    const int* dst = ei + E;
    float* out = (float*)d_out;

    auto A256 = [](size_t v) { return (v + 255) & ~(size_t)255; };

    // fp32-hA layout (single fp16 rounding on layer-1 g): ~103 MB.
    const size_t need_f32 = A256((size_t)N * 4) + 2 * A256((size_t)D * D * 2)
                          + A256((size_t)N * CAP * 4) + A256((size_t)N * D * 4)
                          + A256((size_t)N * D * 2);
    const bool f32 = (ws_size == 0) || (need_f32 <= ws_size);

    char* w = (char*)d_ws;
    int*      cnt = (int*)w;      w += A256((size_t)N * 4);
    _Float16* WT1 = (_Float16*)w; w += A256((size_t)D * D * 2);
    _Float16* WT2 = (_Float16*)w; w += A256((size_t)D * D * 2);
    int*      ep  = (int*)w;      w += A256((size_t)N * CAP * 4);
    void*     hA  = (void*)w;     w += f32 ? A256((size_t)N * D * 4) : A256((size_t)N * D * 2);
    _Float16* g1  = (_Float16*)w;                 // 25.6 MB
    _Float16* g2  = (_Float16*)hA;                // hA dead after k_scale; reuse

    const int egrid = (E + 255) / 256;     // 6250 edge blocks (1 edge/thread, r0-proven)
    const int ggrid = (N + 63) / 64;       // 1563 GEMM blocks
    const int sgrid = (N * (D / 8) + 255) / 256;

    hipMemsetAsync(cnt, 0, (size_t)N * 4, stream);
    k_prepW2<<<(2 * D * D + 255) / 256, 256, 0, stream>>>(W1, W2, WT1, WT2);

    // GEMM1 (-> hA) first, edge scatter trickles in behind (overlap, proven r1/r2)
    if (f32)
        k_fused1<true><<<ggrid + egrid, 256, 0, stream>>>(src, dst, cnt, ep, E, ggrid,
                                                          x, WT1, hA, N);
    else
        k_fused1<false><<<ggrid + egrid, 256, 0, stream>>>(src, dst, cnt, ep, E, ggrid,
                                                           x, WT1, hA, N);

    // g1 = dis * hA  (N-scale pass, ~12us)
    if (f32)
        k_scale<true><<<sgrid, 256, 0, stream>>>(hA, cnt, g1, N);
    else
        k_scale<false><<<sgrid, 256, 0, stream>>>(hA, cnt, g1, N);

    // agg(layer1) + GEMM2 fused; epilogue emits pre-scaled g2 = dis * (h1 W2)
    k_agg_gemm2<<<(N + 31) / 32, 128, 0, stream>>>(g1, cnt, ep, b1, WT2, g2, N);

    // final aggregation -> d_out
    k_agg_out<<<(N + 7) / 8, 256, 0, stream>>>(g2, cnt, ep, b2, out, N);
}